// Round 15
// baseline (278.656 us; speedup 1.0000x reference)
//
#include <hip/hip_runtime.h>

// Fused MHA: B=4, F=2048, D_HIDDEN=1024, H=16, D=64.
// wtrans ; gemm_proj3 (fp32 A read direct + reg-staged cvt, 1-iter A prefetch;
// z0=qh*SC2, z1=kh, z2=vhT via LDS-transpose epilogue) ; masksum ;
// flash attn v9 (8 waves, QBLK=256, proven 112.7us) ; out GEMM (fp32 out).
// ws ~40 MB; qh/kh (bf16) parked in d_out (exact fit, overwritten at end).
// r15 = r14 (proven 268us) with cvt3 ELIMINATED: gemm_proj3 stages fp32 A
// in-kernel (r7-proven numerics) with one-iteration register prefetch (fixes
// r7's exposed-latency chain); vhT epilogue stays r11's proven LDS transpose.
// Tripwire: gemm_proj3 >105us => A-chain latency-exposed, revert to r14.

typedef unsigned short u16;
typedef __attribute__((ext_vector_type(8))) short short8;
typedef __attribute__((ext_vector_type(4))) float f32x4;
typedef __attribute__((ext_vector_type(16))) float f32x16;

#define SC2 0.18033688011112042f         // 0.125 * log2(e) (folded into qh)
#define MSC -1.4426950408889634e9f       // -1e9 * log2(e)
#define THR 8.0f                         // defer-max threshold (log2 space)

__device__ __forceinline__ u16 f2bf(float x) {  // RNE fp32->bf16 (finite inputs)
  unsigned int u = __float_as_uint(x);
  u += 0x7FFFu + ((u >> 16) & 1u);
  return (u16)(u >> 16);
}

__device__ __forceinline__ void gload16(const void* g, void* l) {
  __builtin_amdgcn_global_load_lds(
      (const __attribute__((address_space(1))) void*)g,
      (__attribute__((address_space(3))) void*)l, 16, 0, 0);
}

__device__ __forceinline__ uint4 pack8(const u16* t) {
  uint4 o;
  o.x = (unsigned)t[0] | ((unsigned)t[1] << 16);
  o.y = (unsigned)t[2] | ((unsigned)t[3] << 16);
  o.z = (unsigned)t[4] | ((unsigned)t[5] << 16);
  o.w = (unsigned)t[6] | ((unsigned)t[7] << 16);
  return o;
}

__device__ __forceinline__ unsigned cvtpk(float lo, float hi) {
  unsigned r;
  asm("v_cvt_pk_bf16_f32 %0, %1, %2" : "=v"(r) : "v"(lo), "v"(hi));
  return r;
}

// ---------- mask summary: msum[b][kt][row] = any(mask[b][row][kt*64 .. +63] != 0) ----------
__global__ __launch_bounds__(256) void masksum(const float* __restrict__ mask,
                                               unsigned char* __restrict__ msum) {
  int t = blockIdx.x * 256 + threadIdx.x;   // t = b*65536 + kt*2048 + row
  int row = t & 2047;
  int kt = (t >> 11) & 31;
  int b = t >> 16;
  const float4* p =
      (const float4*)(mask + ((size_t)(b * 2048 + row)) * 2048 + kt * 64);
  unsigned acc = 0;
#pragma unroll
  for (int i = 0; i < 16; i++) {
    float4 f = p[i];
    acc |= __float_as_uint(f.x) | __float_as_uint(f.y) |
           __float_as_uint(f.z) | __float_as_uint(f.w);
  }
  msum[t] = acc ? 1 : 0;
}

// ---------- transpose + cvt: W[1024][1024] fp32 -> WT[1024][1024] bf16 ----------
__global__ __launch_bounds__(256) void wtrans(
    const float* __restrict__ w0, const float* __restrict__ w1,
    const float* __restrict__ w2, const float* __restrict__ w3,
    u16* __restrict__ o0, u16* __restrict__ o1,
    u16* __restrict__ o2, u16* __restrict__ o3) {
  const float* W; u16* O;
  switch (blockIdx.z) {
    case 0: W = w0; O = o0; break;
    case 1: W = w1; O = o1; break;
    case 2: W = w2; O = o2; break;
    default: W = w3; O = o3; break;
  }
  __shared__ u16 T[64][72];
  const int t = threadIdx.x, r = t >> 2, seg = t & 3;
  const int k0 = blockIdx.y * 64, n0 = blockIdx.x * 64;
  const float* src = W + (size_t)(k0 + r) * 1024 + n0 + seg * 16;
#pragma unroll
  for (int jj = 0; jj < 4; jj++) {
    float4 f = ((const float4*)src)[jj];
    T[r][seg * 16 + jj * 4 + 0] = f2bf(f.x);
    T[r][seg * 16 + jj * 4 + 1] = f2bf(f.y);
    T[r][seg * 16 + jj * 4 + 2] = f2bf(f.z);
    T[r][seg * 16 + jj * 4 + 3] = f2bf(f.w);
  }
  __syncthreads();
  u16 tmp[16];
#pragma unroll
  for (int j = 0; j < 16; j++) tmp[j] = T[seg * 16 + j][r];
  u16* dst = O + (size_t)(n0 + r) * 1024 + k0 + seg * 16;
  ((uint4*)dst)[0] = pack8(tmp);
  ((uint4*)dst)[1] = pack8(tmp + 8);
}

// ---------- fused projection GEMMs, fp32 A direct ----------
// z=0 qh(*SC2), z=1 kh, z=2 vhT (transposed epilogue).
// A fp32 [8192][1024] reg-staged->bf16 LDS with 1-iter prefetch; B gload_lds.
__global__ __launch_bounds__(256) void gemm_proj3(
    const float* __restrict__ Aq, const float* __restrict__ Ak,
    const float* __restrict__ Av, const u16* __restrict__ Wq,
    const u16* __restrict__ Wk, const u16* __restrict__ Wv,
    const float* __restrict__ bq, const float* __restrict__ bk,
    const float* __restrict__ bv, u16* __restrict__ oq,
    u16* __restrict__ ok, u16* __restrict__ ovT) {
  constexpr int K = 1024, N = 1024;
  __shared__ u16 sbuf[128 * 136];  // 34.8 KB; K-loop uses first 16 KB (lsA|lsB)
  u16* lsA = sbuf;
  u16* lsB = sbuf + 128 * 32;
  const int z = blockIdx.z;
  const float* A = (z == 0) ? Aq : (z == 1) ? Ak : Av;
  const u16* Bt = (z == 0) ? Wq : (z == 1) ? Wk : Wv;
  const float* bias = (z == 0) ? bq : (z == 1) ? bk : bv;

  const int tid = threadIdx.x;
  const int w = tid >> 6, lane = tid & 63;
  const int l15 = lane & 15, lg = lane >> 4;
  const int m0 = blockIdx.y << 7, n0 = blockIdx.x << 7;
  const int wr = w >> 1, wc = w & 1;

  f32x4 acc[4][4];
#pragma unroll
  for (int i = 0; i < 4; i++)
#pragma unroll
    for (int j = 0; j < 4; j++) acc[i][j] = f32x4{0.f, 0.f, 0.f, 0.f};

  const float* As = A + (size_t)(m0 + w * 32 + (lane >> 2)) * K + (lane & 3) * 8;
  const u16* Bs = Bt + (size_t)(n0 + w * 32 + (lane >> 2)) * K + (lane & 3) * 8;
  u16* lB = &lsB[(w * 32) * 32];
  u16* lAw = &lsA[(w * 32 + (lane >> 2)) * 32 + (lane & 3) * 8];

  // prologue: prefetch A regs for k0=0
  float4 a0 = *(const float4*)(As);
  float4 a1 = *(const float4*)(As + 4);
  float4 a2 = *(const float4*)(As + 16 * K);
  float4 a3 = *(const float4*)(As + 16 * K + 4);

  for (int k0 = 0; k0 < K; k0 += 32) {
    gload16(Bs + k0, lB);
    gload16(Bs + 16 * K + k0, lB + 16 * 32);
    // pack prefetched fp32 -> bf16, write LDS (prev MFMA phase done: loop top
    // is after previous iteration's trailing barrier)
    uint4 pa, pb;
    pa.x = cvtpk(a0.x, a0.y); pa.y = cvtpk(a0.z, a0.w);
    pa.z = cvtpk(a1.x, a1.y); pa.w = cvtpk(a1.z, a1.w);
    pb.x = cvtpk(a2.x, a2.y); pb.y = cvtpk(a2.z, a2.w);
    pb.z = cvtpk(a3.x, a3.y); pb.w = cvtpk(a3.z, a3.w);
    *(uint4*)lAw = pa;
    *(uint4*)(lAw + 16 * 32) = pb;
    // issue next iteration's A loads; latency hides under MFMA + barriers
    if (k0 + 32 < K) {
      a0 = *(const float4*)(As + k0 + 32);
      a1 = *(const float4*)(As + k0 + 36);
      a2 = *(const float4*)(As + 16 * K + k0 + 32);
      a3 = *(const float4*)(As + 16 * K + k0 + 36);
    }
    __syncthreads();
    short8 af[4], bfv[4];
#pragma unroll
    for (int mi = 0; mi < 4; mi++)
      af[mi] = *(const short8*)&lsA[(wr * 64 + mi * 16 + l15) * 32 + lg * 8];
#pragma unroll
    for (int nj = 0; nj < 4; nj++)
      bfv[nj] = *(const short8*)&lsB[(wc * 64 + nj * 16 + l15) * 32 + lg * 8];
#pragma unroll
    for (int mi = 0; mi < 4; mi++)
#pragma unroll
      for (int nj = 0; nj < 4; nj++)
        acc[mi][nj] = __builtin_amdgcn_mfma_f32_16x16x32_bf16(af[mi], bfv[nj],
                                                              acc[mi][nj], 0, 0, 0);
    __syncthreads();
  }

  const int crow = m0 + wr * 64 + lg * 4;
  const int ccol = n0 + wc * 64 + l15;
  if (z < 2) {
    u16* C = (z == 0) ? oq : ok;
    const float scl = (z == 0) ? SC2 : 1.0f;
#pragma unroll
    for (int nj = 0; nj < 4; nj++) {
      float bv = bias[ccol + nj * 16];
#pragma unroll
      for (int mi = 0; mi < 4; mi++)
#pragma unroll
        for (int r = 0; r < 4; r++)
          C[(size_t)(crow + mi * 16 + r) * N + ccol + nj * 16] =
              f2bf((acc[mi][nj][r] + bv) * scl);
    }
  } else {
    // ---- vhT epilogue: LDS transpose, then 128B-contiguous stores ----
    const int rl = wr * 64 + lg * 4;     // local f row base
    const int cl = wc * 64 + l15;        // local d col
#pragma unroll
    for (int nj = 0; nj < 4; nj++) {
      float bv = bias[ccol + nj * 16];
#pragma unroll
      for (int mi = 0; mi < 4; mi++)
#pragma unroll
        for (int r = 0; r < 4; r++)
          sbuf[(rl + mi * 16 + r) * 136 + cl + nj * 16] =
              f2bf(acc[mi][nj][r] + bv);
    }
    __syncthreads();
    const int drow = tid >> 1, seg = tid & 1;
    const int b = m0 >> 11;              // 128-row tile lies in one batch
    const int f0 = (m0 & 2047) + seg * 64;
    u16* dst = ovT + (size_t)(b * 1024 + n0 + drow) * 2048 + f0;
#pragma unroll
    for (int c = 0; c < 8; c++) {
      u16 tmp[8];
#pragma unroll
      for (int j = 0; j < 8; j++)
        tmp[j] = sbuf[(seg * 64 + c * 8 + j) * 136 + drow];
      ((uint4*)dst)[c] = pack8(tmp);
    }
  }
}

// ---------- out-projection GEMM: bf16 A * bf16 W^T -> fp32 ----------
__global__ __launch_bounds__(256) void gemm_out(
    const u16* __restrict__ A, const u16* __restrict__ Bt,
    float* __restrict__ C) {
  constexpr int K = 1024, N = 1024;
  __shared__ u16 lsA[128 * 32];
  __shared__ u16 lsB[128 * 32];
  const int tid = threadIdx.x;
  const int w = tid >> 6, lane = tid & 63;
  const int l15 = lane & 15, lg = lane >> 4;
  const int m0 = blockIdx.y << 7, n0 = blockIdx.x << 7;
  const int wr = w >> 1, wc = w & 1;

  f32x4 acc[4][4];
#pragma unroll
  for (int i = 0; i < 4; i++)
#pragma unroll
    for (int j = 0; j < 4; j++) acc[i][j] = f32x4{0.f, 0.f, 0.f, 0.f};

  const u16* As = A + (size_t)(m0 + w * 32 + (lane >> 2)) * K + (lane & 3) * 8;
  const u16* Bs = Bt + (size_t)(n0 + w * 32 + (lane >> 2)) * K + (lane & 3) * 8;
  u16* lA = &lsA[(w * 32) * 32];
  u16* lB = &lsB[(w * 32) * 32];

  for (int k0 = 0; k0 < K; k0 += 32) {
    gload16(As + k0, lA);
    gload16(As + 16 * K + k0, lA + 16 * 32);
    gload16(Bs + k0, lB);
    gload16(Bs + 16 * K + k0, lB + 16 * 32);
    __syncthreads();
    short8 af[4], bfv[4];
#pragma unroll
    for (int mi = 0; mi < 4; mi++)
      af[mi] = *(const short8*)&lsA[(wr * 64 + mi * 16 + l15) * 32 + lg * 8];
#pragma unroll
    for (int nj = 0; nj < 4; nj++)
      bfv[nj] = *(const short8*)&lsB[(wc * 64 + nj * 16 + l15) * 32 + lg * 8];
#pragma unroll
    for (int mi = 0; mi < 4; mi++)
#pragma unroll
      for (int nj = 0; nj < 4; nj++)
        acc[mi][nj] = __builtin_amdgcn_mfma_f32_16x16x32_bf16(af[mi], bfv[nj],
                                                              acc[mi][nj], 0, 0, 0);
    __syncthreads();
  }

  const int crow = m0 + wr * 64 + lg * 4;
  const int ccol = n0 + wc * 64 + l15;
#pragma unroll
  for (int nj = 0; nj < 4; nj++)
#pragma unroll
    for (int mi = 0; mi < 4; mi++)
#pragma unroll
      for (int r = 0; r < 4; r++)
        C[(size_t)(crow + mi * 16 + r) * N + ccol + nj * 16] = acc[mi][nj][r];
}

// ---------- flash attention v9 (byte-identical to r14, proven 112.7us) ----------
// grid 512 (XCD-swizzled): virt blk = ((b*16+h)*8 + qtile).
// 8 waves; wave owns 32 q-rows (q = lane&31); KTILE=64, dbuf, 1 barrier/tile.
__global__ __launch_bounds__(512, 4) void attn_fwd(
    const u16* __restrict__ qh, const u16* __restrict__ kh,
    const u16* __restrict__ vhT, const float* __restrict__ mask,
    const unsigned char* __restrict__ msum, u16* __restrict__ aout) {
  __shared__ u16 Kls[2][64][72];   // [buf][krow][d]
  __shared__ u16 Vls[2][64][72];   // [buf][d][kcol] (V^T)

  const int tid = threadIdx.x;
  const int w = tid >> 6, lane = tid & 63;
  const int l31 = lane & 31, hi = lane >> 5;
  const int blk = ((blockIdx.x & 7) << 6) | (blockIdx.x >> 3);
  const int qt = blk & 7, bh = blk >> 3, h = bh & 15, b = bh >> 4;
  const int frow = qt * 256 + w * 32;            // q row within batch b
  const size_t qrow0 = (size_t)b * 2048 + frow;  // q row in [8192]

  // Q B-frag: lane holds q-row = l31, d = ds*16 + hi*8 + j  (qh pre-scaled SC2)
  short8 qf[4];
#pragma unroll
  for (int ds = 0; ds < 4; ds++)
    qf[ds] = *(const short8*)&qh[(qrow0 + l31) * 1024 + h * 64 + ds * 16 + hi * 8];

  // loop-invariant zero bank: C-operand of each chain's first MFMA
  f32x16 zf;
#pragma unroll
  for (int i = 0; i < 16; i++) zf[i] = 0.f;

  f32x16 oacc[2];
#pragma unroll
  for (int i = 0; i < 16; i++) { oacc[0][i] = 0.f; oacc[1][i] = 0.f; }
  float m_run = 0.f, l_run = 0.f;  // log2 space; m stays 0 on unmasked path

  const int sr = tid >> 3, seg = tid & 7;  // staging: row 0..63, 16B chunk 0..7
  const u16* Ksrc = kh + ((size_t)b * 2048 + sr) * 1024 + h * 64 + seg * 8;
  const u16* Vsrc = vhT + ((size_t)bh * 64 + sr) * 2048 + seg * 8;
  const unsigned char* msrow = msum + (size_t)b * 65536 + frow + l31;

  uint4 ka0, va0;
  unsigned char mb, mbn;
  {  // prologue: tile 0 -> LDS[0]; prefetch tile 1 into regs
    uint4 x0 = *(const uint4*)Ksrc;
    uint4 y0 = *(const uint4*)Vsrc;
    *(uint4*)&Kls[0][sr][seg * 8] = x0;
    *(uint4*)&Vls[0][sr][seg * 8] = y0;
    ka0 = *(const uint4*)(Ksrc + 64 * 1024);
    va0 = *(const uint4*)(Vsrc + 64);
    mb = msrow[0];
    mbn = msrow[2048];
  }
  __syncthreads();

  for (int kt = 0; kt < 32; kt++) {
    const int cur = kt & 1;
    const int k0 = kt * 64;
    const int mflag = __any((int)mb);
    mb = mbn;

    // write prefetched tile kt+1 -> LDS[cur^1]; issue loads for tile kt+2
    if (kt < 31) {
      *(uint4*)&Kls[cur ^ 1][sr][seg * 8] = ka0;
      *(uint4*)&Vls[cur ^ 1][sr][seg * 8] = va0;
    }
    if (kt < 30) {
      ka0 = *(const uint4*)(Ksrc + (size_t)(kt + 2) * 64 * 1024);
      va0 = *(const uint4*)(Vsrc + (kt + 2) * 64);
      mbn = msrow[(size_t)(kt + 2) * 2048];
    }

    // ---- S^T = K * Q^T (log2 units): k = kb*32 + (reg&3)+8(reg>>2)+4hi, q = l31 ----
    f32x16 sacc[2];
#pragma unroll
    for (int kb = 0; kb < 2; kb++) {
      short8 kf[4];
#pragma unroll
      for (int ds = 0; ds < 4; ds++)
        kf[ds] = *(const short8*)&Kls[cur][kb * 32 + l31][ds * 16 + hi * 8];
      __builtin_amdgcn_s_setprio(1);
      sacc[kb] = __builtin_amdgcn_mfma_f32_32x32x16_bf16(kf[0], qf[0], zf, 0, 0, 0);
#pragma unroll
      for (int ds = 1; ds < 4; ds++)
        sacc[kb] = __builtin_amdgcn_mfma_f32_32x32x16_bf16(kf[ds], qf[ds],
                                                           sacc[kb], 0, 0, 0);
      __builtin_amdgcn_s_setprio(0);
    }

    // ---- masked path only: apply mask, exact max + defer-rescale ----
    if (mflag) {
      const size_t mrow = ((size_t)b * 2048 + frow + l31) * 2048 + (size_t)k0;
#pragma unroll
      for (int kb = 0; kb < 2; kb++)
#pragma unroll
        for (int r = 0; r < 16; r++) {
          float mv = mask[mrow + kb * 32 + (r & 3) + 8 * (r >> 2) + 4 * hi];
          sacc[kb][r] = fmaf(mv, MSC, sacc[kb][r]);
        }
      float mx[16];
#pragma unroll
      for (int r = 0; r < 16; r++) mx[r] = fmaxf(sacc[0][r], sacc[1][r]);
#pragma unroll
      for (int s = 8; s >= 1; s >>= 1)
#pragma unroll
        for (int r = 0; r < s; r++) mx[r] = fmaxf(mx[r], mx[r + s]);
      float tm = mx[0];
      tm = fmaxf(tm, __shfl_xor(tm, 32, 64));
      if (!__all(tm <= m_run + THR)) {
        float mnew = fmaxf(m_run, tm);
        float al = exp2f(m_run - mnew);
        m_run = mnew;
        l_run *= al;
#pragma unroll
        for (int r = 0; r < 16; r++) {
          float alr = __shfl(al, (r & 3) + 8 * (r >> 2) + 4 * hi, 64);
          oacc[0][r] *= alr;
          oacc[1][r] *= alr;
        }
      }
    }

    // ---- exp + sum + pack + permlane32_swap (wave-uniform offset branch) ----
    float rsp = 0.f, rsq = 0.f;
    unsigned pw[16];
    if (m_run == 0.f) {  // fast path: bare exp2, no offset
#pragma unroll
      for (int kb = 0; kb < 2; kb++)
#pragma unroll
        for (int jp = 0; jp < 2; jp++) {
          float e[8];
#pragma unroll
          for (int t = 0; t < 8; t++)
            e[t] = exp2f(sacc[kb][8 * jp + t]);
          rsp += (e[0] + e[1]) + (e[2] + e[3]);
          rsq += (e[4] + e[5]) + (e[6] + e[7]);
          unsigned ye0 = cvtpk(e[0], e[1]);
          unsigned ye1 = cvtpk(e[2], e[3]);
          unsigned xo0 = cvtpk(e[4], e[5]);
          unsigned xo1 = cvtpk(e[6], e[7]);
          asm volatile("v_permlane32_swap_b32 %0, %1" : "+v"(ye0), "+v"(xo0));
          asm volatile("v_permlane32_swap_b32 %0, %1" : "+v"(ye1), "+v"(xo1));
          const int kk = kb * 2 + jp;
          pw[kk * 4 + 0] = ye0;
          pw[kk * 4 + 1] = ye1;
          pw[kk * 4 + 2] = xo0;
          pw[kk * 4 + 3] = xo1;
        }
    } else {  // masked-history path: offset by m_run
      const float mm = m_run;
#pragma unroll
      for (int kb = 0; kb < 2; kb++)
#pragma unroll
        for (int jp = 0; jp < 2; jp++) {
          float e[8];
#pragma unroll
          for (int t = 0; t < 8; t++)
            e[t] = exp2f(sacc[kb][8 * jp + t] - mm);
          rsp += (e[0] + e[1]) + (e[2] + e[3]);
          rsq += (e[4] + e[5]) + (e[6] + e[7]);
          unsigned ye0 = cvtpk(e[0], e[1]);
          unsigned ye1 = cvtpk(e[2], e[3]);
          unsigned xo0 = cvtpk(e[4], e[5]);
          unsigned xo1 = cvtpk(e[6], e[7]);
          asm volatile("v_permlane32_swap_b32 %0, %1" : "+v"(ye0), "+v"(xo0));
          asm volatile("v_permlane32_swap_b32 %0, %1" : "+v"(ye1), "+v"(xo1));
          const int kk = kb * 2 + jp;
          pw[kk * 4 + 0] = ye0;
          pw[kk * 4 + 1] = ye1;
          pw[kk * 4 + 2] = xo0;
          pw[kk * 4 + 3] = xo1;
        }
    }
    float rs = rsp + rsq;
    rs += __shfl_xor(rs, 32, 64);
    l_run += rs;

    // ---- O += P * V ----
#pragma unroll
    for (int dn = 0; dn < 2; dn++) {
      short8 vf[4];
#pragma unroll
      for (int kk = 0; kk < 4; kk++)
        vf[kk] = *(const short8*)&Vls[cur][dn * 32 + l31][kk * 16 + hi * 8];
      __builtin_amdgcn_s_setprio(1);
#pragma unroll
      for (int kk = 0; kk < 4; kk++) {
        uint4 t4 = {pw[kk * 4 + 0], pw[kk * 4 + 1], pw[kk * 4 + 2], pw[kk * 4 + 3]};
        oacc[dn] = __builtin_amdgcn_mfma_f32_32x32x16_bf16(
            *(short8*)&t4, vf[kk], oacc[dn], 0, 0, 0);
      }
      __builtin_amdgcn_s_setprio(0);
    }

    __syncthreads();
  }

  // ---- epilogue: O / l ----
  float inv = 1.0f / l_run;
#pragma unroll
  for (int r = 0; r < 16; r++) {
    const int qr = (r & 3) + 8 * (r >> 2) + 4 * hi;
    float invr = __shfl(inv, qr, 64);
    aout[(qrow0 + qr) * 1024 + h * 64 + l31] = f2bf(oacc[0][r] * invr);
    aout[(qrow0 + qr) * 1024 + h * 64 + 32 + l31] = f2bf(oacc[1][r] * invr);
  }
}

extern "C" void kernel_launch(void* const* d_in, const int* in_sizes, int n_in,
                              void* d_out, int out_size, void* d_ws, size_t ws_size,
                              hipStream_t stream) {
  (void)in_sizes; (void)n_in; (void)out_size; (void)ws_size;
  const float* q    = (const float*)d_in[0];
  const float* k    = (const float*)d_in[1];
  const float* v    = (const float*)d_in[2];
  const float* mask = (const float*)d_in[3];
  const float* qw_w = (const float*)d_in[4];
  const float* qw_b = (const float*)d_in[5];
  const float* kw_w = (const float*)d_in[6];
  const float* kw_b = (const float*)d_in[7];
  const float* vw_w = (const float*)d_in[8];
  const float* vw_b = (const float*)d_in[9];
  const float* wo   = (const float*)d_in[10];

  // workspace layout (u16 elems); total ~40.3 MB
  u16* vhT = (u16*)d_ws;               // 4096*2048 = 16 MB
  u16* qwT = vhT + 4096 * 2048;        // 4x 1024*1024 = 8 MB
  u16* kwT = qwT + 1024 * 1024;
  u16* vwT = kwT + 1024 * 1024;
  u16* woT = vwT + 1024 * 1024;
  u16* attn_o = woT + 1024 * 1024;     // 8192*1024 = 16 MB
  unsigned char* msumb = (unsigned char*)(attn_o + 8192 * 1024);  // 256 KB
  u16* qh = (u16*)d_out;               // park bf16 qh/kh in d_out (exact fit)
  u16* kh = qh + 8192 * 1024;

  wtrans<<<dim3(16, 16, 4), 256, 0, stream>>>(qw_w, kw_w, vw_w, wo,
                                              qwT, kwT, vwT, woT);
  gemm_proj3<<<dim3(8, 64, 3), 256, 0, stream>>>(q, k, v, qwT, kwT, vwT,
                                                 qw_b, kw_b, vw_b, qh, kh, vhT);
  masksum<<<1024, 256, 0, stream>>>(mask, msumb);  // right before attn: L2 flush
  attn_fwd<<<512, 512, 0, stream>>>(qh, kh, vhT, mask, msumb, attn_o);
  gemm_out<<<dim3(8, 64), 256, 0, stream>>>(attn_o, woT, (float*)d_out);
}

// Round 16
// 254.623 us; speedup vs baseline: 1.0944x; 1.0944x over previous
//
#include <hip/hip_runtime.h>

// Fused MHA: B=4, F=2048, D_HIDDEN=1024, H=16, D=64.
// wtrans ; gemm_proj3 (fp32 A direct, XCD-swizzled blocks; z0=qh*SC2, z1=kh,
// z2=vhT via LDS-transpose epilogue) ; masksum ; flash attn v9 (proven
// 112.7us) ; out GEMM (fp32 out).
// ws ~40 MB; qh/kh (bf16) parked in d_out (exact fit, overwritten at end).
// r16 = r15 with ONE fix: XCD-aware bijective block swizzle in gemm_proj3
// (fid=(x+8y); virt=(fid&7)*64+(fid>>3)) so each XCD owns whole m-panels --
// r15's 396MB FETCH was the 8 n-blocks of each m-panel landing on 8 XCDs,
// each re-fetching the fp32 A-panel (T1 mechanism). Everything else identical.
// Tripwire: gemm_proj3 >105us => revert to r14 cvt3 pipeline.

typedef unsigned short u16;
typedef __attribute__((ext_vector_type(8))) short short8;
typedef __attribute__((ext_vector_type(4))) float f32x4;
typedef __attribute__((ext_vector_type(16))) float f32x16;

#define SC2 0.18033688011112042f         // 0.125 * log2(e) (folded into qh)
#define MSC -1.4426950408889634e9f       // -1e9 * log2(e)
#define THR 8.0f                         // defer-max threshold (log2 space)

__device__ __forceinline__ u16 f2bf(float x) {  // RNE fp32->bf16 (finite inputs)
  unsigned int u = __float_as_uint(x);
  u += 0x7FFFu + ((u >> 16) & 1u);
  return (u16)(u >> 16);
}

__device__ __forceinline__ void gload16(const void* g, void* l) {
  __builtin_amdgcn_global_load_lds(
      (const __attribute__((address_space(1))) void*)g,
      (__attribute__((address_space(3))) void*)l, 16, 0, 0);
}

__device__ __forceinline__ uint4 pack8(const u16* t) {
  uint4 o;
  o.x = (unsigned)t[0] | ((unsigned)t[1] << 16);
  o.y = (unsigned)t[2] | ((unsigned)t[3] << 16);
  o.z = (unsigned)t[4] | ((unsigned)t[5] << 16);
  o.w = (unsigned)t[6] | ((unsigned)t[7] << 16);
  return o;
}

__device__ __forceinline__ unsigned cvtpk(float lo, float hi) {
  unsigned r;
  asm("v_cvt_pk_bf16_f32 %0, %1, %2" : "=v"(r) : "v"(lo), "v"(hi));
  return r;
}

// ---------- mask summary: msum[b][kt][row] = any(mask[b][row][kt*64 .. +63] != 0) ----------
__global__ __launch_bounds__(256) void masksum(const float* __restrict__ mask,
                                               unsigned char* __restrict__ msum) {
  int t = blockIdx.x * 256 + threadIdx.x;   // t = b*65536 + kt*2048 + row
  int row = t & 2047;
  int kt = (t >> 11) & 31;
  int b = t >> 16;
  const float4* p =
      (const float4*)(mask + ((size_t)(b * 2048 + row)) * 2048 + kt * 64);
  unsigned acc = 0;
#pragma unroll
  for (int i = 0; i < 16; i++) {
    float4 f = p[i];
    acc |= __float_as_uint(f.x) | __float_as_uint(f.y) |
           __float_as_uint(f.z) | __float_as_uint(f.w);
  }
  msum[t] = acc ? 1 : 0;
}

// ---------- transpose + cvt: W[1024][1024] fp32 -> WT[1024][1024] bf16 ----------
__global__ __launch_bounds__(256) void wtrans(
    const float* __restrict__ w0, const float* __restrict__ w1,
    const float* __restrict__ w2, const float* __restrict__ w3,
    u16* __restrict__ o0, u16* __restrict__ o1,
    u16* __restrict__ o2, u16* __restrict__ o3) {
  const float* W; u16* O;
  switch (blockIdx.z) {
    case 0: W = w0; O = o0; break;
    case 1: W = w1; O = o1; break;
    case 2: W = w2; O = o2; break;
    default: W = w3; O = o3; break;
  }
  __shared__ u16 T[64][72];
  const int t = threadIdx.x, r = t >> 2, seg = t & 3;
  const int k0 = blockIdx.y * 64, n0 = blockIdx.x * 64;
  const float* src = W + (size_t)(k0 + r) * 1024 + n0 + seg * 16;
#pragma unroll
  for (int jj = 0; jj < 4; jj++) {
    float4 f = ((const float4*)src)[jj];
    T[r][seg * 16 + jj * 4 + 0] = f2bf(f.x);
    T[r][seg * 16 + jj * 4 + 1] = f2bf(f.y);
    T[r][seg * 16 + jj * 4 + 2] = f2bf(f.z);
    T[r][seg * 16 + jj * 4 + 3] = f2bf(f.w);
  }
  __syncthreads();
  u16 tmp[16];
#pragma unroll
  for (int j = 0; j < 16; j++) tmp[j] = T[seg * 16 + j][r];
  u16* dst = O + (size_t)(n0 + r) * 1024 + k0 + seg * 16;
  ((uint4*)dst)[0] = pack8(tmp);
  ((uint4*)dst)[1] = pack8(tmp + 8);
}

// ---------- fused projection GEMMs, fp32 A direct, XCD-swizzled ----------
// z=0 qh(*SC2), z=1 kh, z=2 vhT (transposed epilogue).
// A fp32 [8192][1024] reg-staged->bf16 LDS with 1-iter prefetch; B gload_lds.
// Block swizzle: each XCD owns 8 whole m-panels (all n-tiles) -> A L2 reuse.
__global__ __launch_bounds__(256) void gemm_proj3(
    const float* __restrict__ Aq, const float* __restrict__ Ak,
    const float* __restrict__ Av, const u16* __restrict__ Wq,
    const u16* __restrict__ Wk, const u16* __restrict__ Wv,
    const float* __restrict__ bq, const float* __restrict__ bk,
    const float* __restrict__ bv, u16* __restrict__ oq,
    u16* __restrict__ ok, u16* __restrict__ ovT) {
  constexpr int K = 1024, N = 1024;
  __shared__ u16 sbuf[128 * 136];  // 34.8 KB; K-loop uses first 16 KB (lsA|lsB)
  u16* lsA = sbuf;
  u16* lsB = sbuf + 128 * 32;
  const int z = blockIdx.z;
  const float* A = (z == 0) ? Aq : (z == 1) ? Ak : Av;
  const u16* Bt = (z == 0) ? Wq : (z == 1) ? Wk : Wv;
  const float* bias = (z == 0) ? bq : (z == 1) ? bk : bv;

  const int tid = threadIdx.x;
  const int w = tid >> 6, lane = tid & 63;
  const int l15 = lane & 15, lg = lane >> 4;
  // XCD swizzle (bijective, 512 blocks): fid%8 = XCD; give each XCD whole
  // m-panels so all 8 n-tiles of a panel share one L2 (A fetched once).
  const int fid = blockIdx.x + (blockIdx.y << 3);
  const int virt = ((fid & 7) << 6) + (fid >> 3);
  const int m0 = (virt >> 3) << 7, n0 = (virt & 7) << 7;
  const int wr = w >> 1, wc = w & 1;

  f32x4 acc[4][4];
#pragma unroll
  for (int i = 0; i < 4; i++)
#pragma unroll
    for (int j = 0; j < 4; j++) acc[i][j] = f32x4{0.f, 0.f, 0.f, 0.f};

  const float* As = A + (size_t)(m0 + w * 32 + (lane >> 2)) * K + (lane & 3) * 8;
  const u16* Bs = Bt + (size_t)(n0 + w * 32 + (lane >> 2)) * K + (lane & 3) * 8;
  u16* lB = &lsB[(w * 32) * 32];
  u16* lAw = &lsA[(w * 32 + (lane >> 2)) * 32 + (lane & 3) * 8];

  // prologue: prefetch A regs for k0=0
  float4 a0 = *(const float4*)(As);
  float4 a1 = *(const float4*)(As + 4);
  float4 a2 = *(const float4*)(As + 16 * K);
  float4 a3 = *(const float4*)(As + 16 * K + 4);

  for (int k0 = 0; k0 < K; k0 += 32) {
    gload16(Bs + k0, lB);
    gload16(Bs + 16 * K + k0, lB + 16 * 32);
    uint4 pa, pb;
    pa.x = cvtpk(a0.x, a0.y); pa.y = cvtpk(a0.z, a0.w);
    pa.z = cvtpk(a1.x, a1.y); pa.w = cvtpk(a1.z, a1.w);
    pb.x = cvtpk(a2.x, a2.y); pb.y = cvtpk(a2.z, a2.w);
    pb.z = cvtpk(a3.x, a3.y); pb.w = cvtpk(a3.z, a3.w);
    *(uint4*)lAw = pa;
    *(uint4*)(lAw + 16 * 32) = pb;
    // issue next iteration's A loads; latency hides under MFMA + barriers
    if (k0 + 32 < K) {
      a0 = *(const float4*)(As + k0 + 32);
      a1 = *(const float4*)(As + k0 + 36);
      a2 = *(const float4*)(As + 16 * K + k0 + 32);
      a3 = *(const float4*)(As + 16 * K + k0 + 36);
    }
    __syncthreads();
    short8 af[4], bfv[4];
#pragma unroll
    for (int mi = 0; mi < 4; mi++)
      af[mi] = *(const short8*)&lsA[(wr * 64 + mi * 16 + l15) * 32 + lg * 8];
#pragma unroll
    for (int nj = 0; nj < 4; nj++)
      bfv[nj] = *(const short8*)&lsB[(wc * 64 + nj * 16 + l15) * 32 + lg * 8];
#pragma unroll
    for (int mi = 0; mi < 4; mi++)
#pragma unroll
      for (int nj = 0; nj < 4; nj++)
        acc[mi][nj] = __builtin_amdgcn_mfma_f32_16x16x32_bf16(af[mi], bfv[nj],
                                                              acc[mi][nj], 0, 0, 0);
    __syncthreads();
  }

  const int crow = m0 + wr * 64 + lg * 4;
  const int ccol = n0 + wc * 64 + l15;
  if (z < 2) {
    u16* C = (z == 0) ? oq : ok;
    const float scl = (z == 0) ? SC2 : 1.0f;
#pragma unroll
    for (int nj = 0; nj < 4; nj++) {
      float bv = bias[ccol + nj * 16];
#pragma unroll
      for (int mi = 0; mi < 4; mi++)
#pragma unroll
        for (int r = 0; r < 4; r++)
          C[(size_t)(crow + mi * 16 + r) * N + ccol + nj * 16] =
              f2bf((acc[mi][nj][r] + bv) * scl);
    }
  } else {
    // ---- vhT epilogue: LDS transpose, then 128B-contiguous stores ----
    const int rl = wr * 64 + lg * 4;     // local f row base
    const int cl = wc * 64 + l15;        // local d col
#pragma unroll
    for (int nj = 0; nj < 4; nj++) {
      float bv = bias[ccol + nj * 16];
#pragma unroll
      for (int mi = 0; mi < 4; mi++)
#pragma unroll
        for (int r = 0; r < 4; r++)
          sbuf[(rl + mi * 16 + r) * 136 + cl + nj * 16] =
              f2bf(acc[mi][nj][r] + bv);
    }
    __syncthreads();
    const int drow = tid >> 1, seg = tid & 1;
    const int b = m0 >> 11;              // 128-row tile lies in one batch
    const int f0 = (m0 & 2047) + seg * 64;
    u16* dst = ovT + (size_t)(b * 1024 + n0 + drow) * 2048 + f0;
#pragma unroll
    for (int c = 0; c < 8; c++) {
      u16 tmp[8];
#pragma unroll
      for (int j = 0; j < 8; j++)
        tmp[j] = sbuf[(seg * 64 + c * 8 + j) * 136 + drow];
      ((uint4*)dst)[c] = pack8(tmp);
    }
  }
}

// ---------- out-projection GEMM: bf16 A * bf16 W^T -> fp32 ----------
__global__ __launch_bounds__(256) void gemm_out(
    const u16* __restrict__ A, const u16* __restrict__ Bt,
    float* __restrict__ C) {
  constexpr int K = 1024, N = 1024;
  __shared__ u16 lsA[128 * 32];
  __shared__ u16 lsB[128 * 32];
  const int tid = threadIdx.x;
  const int w = tid >> 6, lane = tid & 63;
  const int l15 = lane & 15, lg = lane >> 4;
  const int m0 = blockIdx.y << 7, n0 = blockIdx.x << 7;
  const int wr = w >> 1, wc = w & 1;

  f32x4 acc[4][4];
#pragma unroll
  for (int i = 0; i < 4; i++)
#pragma unroll
    for (int j = 0; j < 4; j++) acc[i][j] = f32x4{0.f, 0.f, 0.f, 0.f};

  const u16* As = A + (size_t)(m0 + w * 32 + (lane >> 2)) * K + (lane & 3) * 8;
  const u16* Bs = Bt + (size_t)(n0 + w * 32 + (lane >> 2)) * K + (lane & 3) * 8;
  u16* lA = &lsA[(w * 32) * 32];
  u16* lB = &lsB[(w * 32) * 32];

  for (int k0 = 0; k0 < K; k0 += 32) {
    gload16(As + k0, lA);
    gload16(As + 16 * K + k0, lA + 16 * 32);
    gload16(Bs + k0, lB);
    gload16(Bs + 16 * K + k0, lB + 16 * 32);
    __syncthreads();
    short8 af[4], bfv[4];
#pragma unroll
    for (int mi = 0; mi < 4; mi++)
      af[mi] = *(const short8*)&lsA[(wr * 64 + mi * 16 + l15) * 32 + lg * 8];
#pragma unroll
    for (int nj = 0; nj < 4; nj++)
      bfv[nj] = *(const short8*)&lsB[(wc * 64 + nj * 16 + l15) * 32 + lg * 8];
#pragma unroll
    for (int mi = 0; mi < 4; mi++)
#pragma unroll
      for (int nj = 0; nj < 4; nj++)
        acc[mi][nj] = __builtin_amdgcn_mfma_f32_16x16x32_bf16(af[mi], bfv[nj],
                                                              acc[mi][nj], 0, 0, 0);
    __syncthreads();
  }

  const int crow = m0 + wr * 64 + lg * 4;
  const int ccol = n0 + wc * 64 + l15;
#pragma unroll
  for (int nj = 0; nj < 4; nj++)
#pragma unroll
    for (int mi = 0; mi < 4; mi++)
#pragma unroll
      for (int r = 0; r < 4; r++)
        C[(size_t)(crow + mi * 16 + r) * N + ccol + nj * 16] = acc[mi][nj][r];
}

// ---------- flash attention v9 (byte-identical to r14, proven 112.7us) ----------
// grid 512 (XCD-swizzled): virt blk = ((b*16+h)*8 + qtile).
// 8 waves; wave owns 32 q-rows (q = lane&31); KTILE=64, dbuf, 1 barrier/tile.
__global__ __launch_bounds__(512, 4) void attn_fwd(
    const u16* __restrict__ qh, const u16* __restrict__ kh,
    const u16* __restrict__ vhT, const float* __restrict__ mask,
    const unsigned char* __restrict__ msum, u16* __restrict__ aout) {
  __shared__ u16 Kls[2][64][72];   // [buf][krow][d]
  __shared__ u16 Vls[2][64][72];   // [buf][d][kcol] (V^T)

  const int tid = threadIdx.x;
  const int w = tid >> 6, lane = tid & 63;
  const int l31 = lane & 31, hi = lane >> 5;
  const int blk = ((blockIdx.x & 7) << 6) | (blockIdx.x >> 3);
  const int qt = blk & 7, bh = blk >> 3, h = bh & 15, b = bh >> 4;
  const int frow = qt * 256 + w * 32;            // q row within batch b
  const size_t qrow0 = (size_t)b * 2048 + frow;  // q row in [8192]

  // Q B-frag: lane holds q-row = l31, d = ds*16 + hi*8 + j  (qh pre-scaled SC2)
  short8 qf[4];
#pragma unroll
  for (int ds = 0; ds < 4; ds++)
    qf[ds] = *(const short8*)&qh[(qrow0 + l31) * 1024 + h * 64 + ds * 16 + hi * 8];

  // loop-invariant zero bank: C-operand of each chain's first MFMA
  f32x16 zf;
#pragma unroll
  for (int i = 0; i < 16; i++) zf[i] = 0.f;

  f32x16 oacc[2];
#pragma unroll
  for (int i = 0; i < 16; i++) { oacc[0][i] = 0.f; oacc[1][i] = 0.f; }
  float m_run = 0.f, l_run = 0.f;  // log2 space; m stays 0 on unmasked path

  const int sr = tid >> 3, seg = tid & 7;  // staging: row 0..63, 16B chunk 0..7
  const u16* Ksrc = kh + ((size_t)b * 2048 + sr) * 1024 + h * 64 + seg * 8;
  const u16* Vsrc = vhT + ((size_t)bh * 64 + sr) * 2048 + seg * 8;
  const unsigned char* msrow = msum + (size_t)b * 65536 + frow + l31;

  uint4 ka0, va0;
  unsigned char mb, mbn;
  {  // prologue: tile 0 -> LDS[0]; prefetch tile 1 into regs
    uint4 x0 = *(const uint4*)Ksrc;
    uint4 y0 = *(const uint4*)Vsrc;
    *(uint4*)&Kls[0][sr][seg * 8] = x0;
    *(uint4*)&Vls[0][sr][seg * 8] = y0;
    ka0 = *(const uint4*)(Ksrc + 64 * 1024);
    va0 = *(const uint4*)(Vsrc + 64);
    mb = msrow[0];
    mbn = msrow[2048];
  }
  __syncthreads();

  for (int kt = 0; kt < 32; kt++) {
    const int cur = kt & 1;
    const int k0 = kt * 64;
    const int mflag = __any((int)mb);
    mb = mbn;

    // write prefetched tile kt+1 -> LDS[cur^1]; issue loads for tile kt+2
    if (kt < 31) {
      *(uint4*)&Kls[cur ^ 1][sr][seg * 8] = ka0;
      *(uint4*)&Vls[cur ^ 1][sr][seg * 8] = va0;
    }
    if (kt < 30) {
      ka0 = *(const uint4*)(Ksrc + (size_t)(kt + 2) * 64 * 1024);
      va0 = *(const uint4*)(Vsrc + (kt + 2) * 64);
      mbn = msrow[(size_t)(kt + 2) * 2048];
    }

    // ---- S^T = K * Q^T (log2 units): k = kb*32 + (reg&3)+8(reg>>2)+4hi, q = l31 ----
    f32x16 sacc[2];
#pragma unroll
    for (int kb = 0; kb < 2; kb++) {
      short8 kf[4];
#pragma unroll
      for (int ds = 0; ds < 4; ds++)
        kf[ds] = *(const short8*)&Kls[cur][kb * 32 + l31][ds * 16 + hi * 8];
      __builtin_amdgcn_s_setprio(1);
      sacc[kb] = __builtin_amdgcn_mfma_f32_32x32x16_bf16(kf[0], qf[0], zf, 0, 0, 0);
#pragma unroll
      for (int ds = 1; ds < 4; ds++)
        sacc[kb] = __builtin_amdgcn_mfma_f32_32x32x16_bf16(kf[ds], qf[ds],
                                                           sacc[kb], 0, 0, 0);
      __builtin_amdgcn_s_setprio(0);
    }

    // ---- masked path only: apply mask, exact max + defer-rescale ----
    if (mflag) {
      const size_t mrow = ((size_t)b * 2048 + frow + l31) * 2048 + (size_t)k0;
#pragma unroll
      for (int kb = 0; kb < 2; kb++)
#pragma unroll
        for (int r = 0; r < 16; r++) {
          float mv = mask[mrow + kb * 32 + (r & 3) + 8 * (r >> 2) + 4 * hi];
          sacc[kb][r] = fmaf(mv, MSC, sacc[kb][r]);
        }
      float mx[16];
#pragma unroll
      for (int r = 0; r < 16; r++) mx[r] = fmaxf(sacc[0][r], sacc[1][r]);
#pragma unroll
      for (int s = 8; s >= 1; s >>= 1)
#pragma unroll
        for (int r = 0; r < s; r++) mx[r] = fmaxf(mx[r], mx[r + s]);
      float tm = mx[0];
      tm = fmaxf(tm, __shfl_xor(tm, 32, 64));
      if (!__all(tm <= m_run + THR)) {
        float mnew = fmaxf(m_run, tm);
        float al = exp2f(m_run - mnew);
        m_run = mnew;
        l_run *= al;
#pragma unroll
        for (int r = 0; r < 16; r++) {
          float alr = __shfl(al, (r & 3) + 8 * (r >> 2) + 4 * hi, 64);
          oacc[0][r] *= alr;
          oacc[1][r] *= alr;
        }
      }
    }

    // ---- exp + sum + pack + permlane32_swap (wave-uniform offset branch) ----
    float rsp = 0.f, rsq = 0.f;
    unsigned pw[16];
    if (m_run == 0.f) {  // fast path: bare exp2, no offset
#pragma unroll
      for (int kb = 0; kb < 2; kb++)
#pragma unroll
        for (int jp = 0; jp < 2; jp++) {
          float e[8];
#pragma unroll
          for (int t = 0; t < 8; t++)
            e[t] = exp2f(sacc[kb][8 * jp + t]);
          rsp += (e[0] + e[1]) + (e[2] + e[3]);
          rsq += (e[4] + e[5]) + (e[6] + e[7]);
          unsigned ye0 = cvtpk(e[0], e[1]);
          unsigned ye1 = cvtpk(e[2], e[3]);
          unsigned xo0 = cvtpk(e[4], e[5]);
          unsigned xo1 = cvtpk(e[6], e[7]);
          asm volatile("v_permlane32_swap_b32 %0, %1" : "+v"(ye0), "+v"(xo0));
          asm volatile("v_permlane32_swap_b32 %0, %1" : "+v"(ye1), "+v"(xo1));
          const int kk = kb * 2 + jp;
          pw[kk * 4 + 0] = ye0;
          pw[kk * 4 + 1] = ye1;
          pw[kk * 4 + 2] = xo0;
          pw[kk * 4 + 3] = xo1;
        }
    } else {  // masked-history path: offset by m_run
      const float mm = m_run;
#pragma unroll
      for (int kb = 0; kb < 2; kb++)
#pragma unroll
        for (int jp = 0; jp < 2; jp++) {
          float e[8];
#pragma unroll
          for (int t = 0; t < 8; t++)
            e[t] = exp2f(sacc[kb][8 * jp + t] - mm);
          rsp += (e[0] + e[1]) + (e[2] + e[3]);
          rsq += (e[4] + e[5]) + (e[6] + e[7]);
          unsigned ye0 = cvtpk(e[0], e[1]);
          unsigned ye1 = cvtpk(e[2], e[3]);
          unsigned xo0 = cvtpk(e[4], e[5]);
          unsigned xo1 = cvtpk(e[6], e[7]);
          asm volatile("v_permlane32_swap_b32 %0, %1" : "+v"(ye0), "+v"(xo0));
          asm volatile("v_permlane32_swap_b32 %0, %1" : "+v"(ye1), "+v"(xo1));
          const int kk = kb * 2 + jp;
          pw[kk * 4 + 0] = ye0;
          pw[kk * 4 + 1] = ye1;
          pw[kk * 4 + 2] = xo0;
          pw[kk * 4 + 3] = xo1;
        }
    }
    float rs = rsp + rsq;
    rs += __shfl_xor(rs, 32, 64);
    l_run += rs;

    // ---- O += P * V ----
#pragma unroll
    for (int dn = 0; dn < 2; dn++) {
      short8 vf[4];
#pragma unroll
      for (int kk = 0; kk < 4; kk++)
        vf[kk] = *(const short8*)&Vls[cur][dn * 32 + l31][kk * 16 + hi * 8];
      __builtin_amdgcn_s_setprio(1);
#pragma unroll
      for (int kk = 0; kk < 4; kk++) {
        uint4 t4 = {pw[kk * 4 + 0], pw[kk * 4 + 1], pw[kk * 4 + 2], pw[kk * 4 + 3]};
        oacc[dn] = __builtin_amdgcn_mfma_f32_32x32x16_bf16(
            *(short8*)&t4, vf[kk], oacc[dn], 0, 0, 0);
      }
      __builtin_amdgcn_s_setprio(0);
    }

    __syncthreads();
  }

  // ---- epilogue: O / l ----
  float inv = 1.0f / l_run;
#pragma unroll
  for (int r = 0; r < 16; r++) {
    const int qr = (r & 3) + 8 * (r >> 2) + 4 * hi;
    float invr = __shfl(inv, qr, 64);
    aout[(qrow0 + qr) * 1024 + h * 64 + l31] = f2bf(oacc[0][r] * invr);
    aout[(qrow0 + qr) * 1024 + h * 64 + 32 + l31] = f2bf(oacc[1][r] * invr);
  }
}

extern "C" void kernel_launch(void* const* d_in, const int* in_sizes, int n_in,
                              void* d_out, int out_size, void* d_ws, size_t ws_size,
                              hipStream_t stream) {
  (void)in_sizes; (void)n_in; (void)out_size; (void)ws_size;
  const float* q    = (const float*)d_in[0];
  const float* k    = (const float*)d_in[1];
  const float* v    = (const float*)d_in[2];
  const float* mask = (const float*)d_in[3];
  const float* qw_w = (const float*)d_in[4];
  const float* qw_b = (const float*)d_in[5];
  const float* kw_w = (const float*)d_in[6];
  const float* kw_b = (const float*)d_in[7];
  const float* vw_w = (const float*)d_in[8];
  const float* vw_b = (const float*)d_in[9];
  const float* wo   = (const float*)d_in[10];

  // workspace layout (u16 elems); total ~40.3 MB
  u16* vhT = (u16*)d_ws;               // 4096*2048 = 16 MB
  u16* qwT = vhT + 4096 * 2048;        // 4x 1024*1024 = 8 MB
  u16* kwT = qwT + 1024 * 1024;
  u16* vwT = kwT + 1024 * 1024;
  u16* woT = vwT + 1024 * 1024;
  u16* attn_o = woT + 1024 * 1024;     // 8192*1024 = 16 MB
  unsigned char* msumb = (unsigned char*)(attn_o + 8192 * 1024);  // 256 KB
  u16* qh = (u16*)d_out;               // park bf16 qh/kh in d_out (exact fit)
  u16* kh = qh + 8192 * 1024;

  wtrans<<<dim3(16, 16, 4), 256, 0, stream>>>(qw_w, kw_w, vw_w, wo,
                                              qwT, kwT, vwT, woT);
  gemm_proj3<<<dim3(8, 64, 3), 256, 0, stream>>>(q, k, v, qwT, kwT, vwT,
                                                 qw_b, kw_b, vw_b, qh, kh, vhT);
  masksum<<<1024, 256, 0, stream>>>(mask, msumb);  // right before attn: L2 flush
  attn_fwd<<<512, 512, 0, stream>>>(qh, kh, vhT, mask, msumb, attn_o);
  gemm_out<<<dim3(8, 64), 256, 0, stream>>>(attn_o, woT, (float*)d_out);
}

// Round 19
// 248.580 us; speedup vs baseline: 1.1210x; 1.0243x over previous
//
#include <hip/hip_runtime.h>

// Fused MHA: B=4, F=2048, D_HIDDEN=1024, H=16, D=64.
// wtrans ; gemm_proj3 (fp32 A direct, XCD swizzle, single-barrier dbuf K-loop;
// z0=qh*SC2, z1=kh, z2=vhT via LDS-transpose epilogue) ; masksum ;
// flash attn v9 (proven 112.7us) ; out GEMM (fp32 out).
// ws ~40 MB; qh/kh (bf16) parked in d_out (exact fit, overwritten at end).
// r19 = r18 with ONE-LINE FIX: A-tile LDS write offset was tid*8 (=w*512+
// lane*8) instead of w*1024+lane*8 -- waves overlapped, garbage A -> NaN.
// Now matches the r16-proven layout. Theory under test unchanged (r17):
// loads issue BEFORE the MFMA phase so the barrier's vmcnt(0) drain is
// covered by ~250cyc of MFMA instead of exposing full L2 latency.

typedef unsigned short u16;
typedef __attribute__((ext_vector_type(8))) short short8;
typedef __attribute__((ext_vector_type(4))) float f32x4;
typedef __attribute__((ext_vector_type(16))) float f32x16;

#define SC2 0.18033688011112042f         // 0.125 * log2(e) (folded into qh)
#define MSC -1.4426950408889634e9f       // -1e9 * log2(e)
#define THR 8.0f                         // defer-max threshold (log2 space)

__device__ __forceinline__ u16 f2bf(float x) {  // RNE fp32->bf16 (finite inputs)
  unsigned int u = __float_as_uint(x);
  u += 0x7FFFu + ((u >> 16) & 1u);
  return (u16)(u >> 16);
}

__device__ __forceinline__ void gload16(const void* g, void* l) {
  __builtin_amdgcn_global_load_lds(
      (const __attribute__((address_space(1))) void*)g,
      (__attribute__((address_space(3))) void*)l, 16, 0, 0);
}

__device__ __forceinline__ uint4 pack8(const u16* t) {
  uint4 o;
  o.x = (unsigned)t[0] | ((unsigned)t[1] << 16);
  o.y = (unsigned)t[2] | ((unsigned)t[3] << 16);
  o.z = (unsigned)t[4] | ((unsigned)t[5] << 16);
  o.w = (unsigned)t[6] | ((unsigned)t[7] << 16);
  return o;
}

__device__ __forceinline__ unsigned cvtpk(float lo, float hi) {
  unsigned r;
  asm("v_cvt_pk_bf16_f32 %0, %1, %2" : "=v"(r) : "v"(lo), "v"(hi));
  return r;
}

// ---------- mask summary: msum[b][kt][row] = any(mask[b][row][kt*64 .. +63] != 0) ----------
__global__ __launch_bounds__(256) void masksum(const float* __restrict__ mask,
                                               unsigned char* __restrict__ msum) {
  int t = blockIdx.x * 256 + threadIdx.x;   // t = b*65536 + kt*2048 + row
  int row = t & 2047;
  int kt = (t >> 11) & 31;
  int b = t >> 16;
  const float4* p =
      (const float4*)(mask + ((size_t)(b * 2048 + row)) * 2048 + kt * 64);
  unsigned acc = 0;
#pragma unroll
  for (int i = 0; i < 16; i++) {
    float4 f = p[i];
    acc |= __float_as_uint(f.x) | __float_as_uint(f.y) |
           __float_as_uint(f.z) | __float_as_uint(f.w);
  }
  msum[t] = acc ? 1 : 0;
}

// ---------- transpose + cvt: W[1024][1024] fp32 -> WT[1024][1024] bf16 ----------
__global__ __launch_bounds__(256) void wtrans(
    const float* __restrict__ w0, const float* __restrict__ w1,
    const float* __restrict__ w2, const float* __restrict__ w3,
    u16* __restrict__ o0, u16* __restrict__ o1,
    u16* __restrict__ o2, u16* __restrict__ o3) {
  const float* W; u16* O;
  switch (blockIdx.z) {
    case 0: W = w0; O = o0; break;
    case 1: W = w1; O = o1; break;
    case 2: W = w2; O = o2; break;
    default: W = w3; O = o3; break;
  }
  __shared__ u16 T[64][72];
  const int t = threadIdx.x, r = t >> 2, seg = t & 3;
  const int k0 = blockIdx.y * 64, n0 = blockIdx.x * 64;
  const float* src = W + (size_t)(k0 + r) * 1024 + n0 + seg * 16;
#pragma unroll
  for (int jj = 0; jj < 4; jj++) {
    float4 f = ((const float4*)src)[jj];
    T[r][seg * 16 + jj * 4 + 0] = f2bf(f.x);
    T[r][seg * 16 + jj * 4 + 1] = f2bf(f.y);
    T[r][seg * 16 + jj * 4 + 2] = f2bf(f.z);
    T[r][seg * 16 + jj * 4 + 3] = f2bf(f.w);
  }
  __syncthreads();
  u16 tmp[16];
#pragma unroll
  for (int j = 0; j < 16; j++) tmp[j] = T[seg * 16 + j][r];
  u16* dst = O + (size_t)(n0 + r) * 1024 + k0 + seg * 16;
  ((uint4*)dst)[0] = pack8(tmp);
  ((uint4*)dst)[1] = pack8(tmp + 8);
}

// ---------- fused projection GEMMs, fp32 A direct, XCD swizzle, dbuf ----------
// z=0 qh(*SC2), z=1 kh, z=2 vhT (transposed epilogue).
// Layout in sbuf (u16): A0 @0, A1 @4096, B0 @8192, B1 @12288.
// Single barrier/iter: issue B gload_lds + pack A-regs + issue next A-regs
// into buf[nxt] BEFORE MFMA on buf[cur]; barrier after MFMA covers drains.
__global__ __launch_bounds__(256) void gemm_proj3(
    const float* __restrict__ Aq, const float* __restrict__ Ak,
    const float* __restrict__ Av, const u16* __restrict__ Wq,
    const u16* __restrict__ Wk, const u16* __restrict__ Wv,
    const float* __restrict__ bq, const float* __restrict__ bk,
    const float* __restrict__ bv, u16* __restrict__ oq,
    u16* __restrict__ ok, u16* __restrict__ ovT) {
  constexpr int K = 1024, N = 1024;
  __shared__ u16 sbuf[128 * 136];  // 34.8 KB; K-loop uses 32 KB as dbuf A|B
  const int z = blockIdx.z;
  const float* A = (z == 0) ? Aq : (z == 1) ? Ak : Av;
  const u16* Bt = (z == 0) ? Wq : (z == 1) ? Wk : Wv;
  const float* bias = (z == 0) ? bq : (z == 1) ? bk : bv;

  const int tid = threadIdx.x;
  const int w = tid >> 6, lane = tid & 63;
  const int l15 = lane & 15, lg = lane >> 4;
  // XCD swizzle (bijective, 512 blocks): each XCD owns whole m-panels.
  const int fid = blockIdx.x + (blockIdx.y << 3);
  const int virt = ((fid & 7) << 6) + (fid >> 3);
  const int m0 = (virt >> 3) << 7, n0 = (virt & 7) << 7;
  const int wr = w >> 1, wc = w & 1;

  f32x4 acc[4][4];
#pragma unroll
  for (int i = 0; i < 4; i++)
#pragma unroll
    for (int j = 0; j < 4; j++) acc[i][j] = f32x4{0.f, 0.f, 0.f, 0.f};

  const float* As = A + (size_t)(m0 + w * 32 + (lane >> 2)) * K + (lane & 3) * 8;
  const u16* Bs = Bt + (size_t)(n0 + w * 32 + (lane >> 2)) * K + (lane & 3) * 8;
  const int lofs = w * 1024 + lane * 8;  // == (w*32 + (lane>>2))*32 + (lane&3)*8

  // prologue: stage iter 0 into buf 0; prefetch A-regs for iter 1
  float4 a0 = *(const float4*)(As);
  float4 a1 = *(const float4*)(As + 4);
  float4 a2 = *(const float4*)(As + 16 * K);
  float4 a3 = *(const float4*)(As + 16 * K + 4);
  gload16(Bs, sbuf + 8192 + w * 1024);
  gload16(Bs + 16 * K, sbuf + 8192 + w * 1024 + 512);
  {
    uint4 pa, pb;
    pa.x = cvtpk(a0.x, a0.y); pa.y = cvtpk(a0.z, a0.w);
    pa.z = cvtpk(a1.x, a1.y); pa.w = cvtpk(a1.z, a1.w);
    pb.x = cvtpk(a2.x, a2.y); pb.y = cvtpk(a2.z, a2.w);
    pb.z = cvtpk(a3.x, a3.y); pb.w = cvtpk(a3.z, a3.w);
    *(uint4*)(sbuf + lofs) = pa;
    *(uint4*)(sbuf + lofs + 512) = pb;
  }
  a0 = *(const float4*)(As + 32);
  a1 = *(const float4*)(As + 36);
  a2 = *(const float4*)(As + 16 * K + 32);
  a3 = *(const float4*)(As + 16 * K + 36);
  __syncthreads();

  for (int kt = 0; kt < 32; kt++) {
    const int cur = kt & 1, nxt = cur ^ 1;
    const int k0n = (kt + 1) * 32;
    u16* lsAc = sbuf + cur * 4096;
    u16* lsBc = sbuf + 8192 + cur * 4096;
    if (kt < 31) {
      // issue next B tile (async to LDS) and pack prefetched A into buf[nxt]
      u16* lsBn = sbuf + 8192 + nxt * 4096;
      gload16(Bs + k0n, lsBn + w * 1024);
      gload16(Bs + 16 * K + k0n, lsBn + w * 1024 + 512);
      uint4 pa, pb;
      pa.x = cvtpk(a0.x, a0.y); pa.y = cvtpk(a0.z, a0.w);
      pa.z = cvtpk(a1.x, a1.y); pa.w = cvtpk(a1.z, a1.w);
      pb.x = cvtpk(a2.x, a2.y); pb.y = cvtpk(a2.z, a2.w);
      pb.z = cvtpk(a3.x, a3.y); pb.w = cvtpk(a3.z, a3.w);
      u16* lsAn = sbuf + nxt * 4096;
      *(uint4*)(lsAn + lofs) = pa;
      *(uint4*)(lsAn + lofs + 512) = pb;
      if (kt < 30) {  // issue A-regs for kt+2; drains at this iter's barrier
        a0 = *(const float4*)(As + k0n + 32);
        a1 = *(const float4*)(As + k0n + 36);
        a2 = *(const float4*)(As + 16 * K + k0n + 32);
        a3 = *(const float4*)(As + 16 * K + k0n + 36);
      }
    }
    // ---- MFMA on buf[cur] (covers the drains of the loads issued above) ----
    short8 af[4], bfv[4];
#pragma unroll
    for (int mi = 0; mi < 4; mi++)
      af[mi] = *(const short8*)&lsAc[(wr * 64 + mi * 16 + l15) * 32 + lg * 8];
#pragma unroll
    for (int nj = 0; nj < 4; nj++)
      bfv[nj] = *(const short8*)&lsBc[(wc * 64 + nj * 16 + l15) * 32 + lg * 8];
#pragma unroll
    for (int mi = 0; mi < 4; mi++)
#pragma unroll
      for (int nj = 0; nj < 4; nj++)
        acc[mi][nj] = __builtin_amdgcn_mfma_f32_16x16x32_bf16(af[mi], bfv[nj],
                                                              acc[mi][nj], 0, 0, 0);
    __syncthreads();
  }

  const int crow = m0 + wr * 64 + lg * 4;
  const int ccol = n0 + wc * 64 + l15;
  if (z < 2) {
    u16* C = (z == 0) ? oq : ok;
    const float scl = (z == 0) ? SC2 : 1.0f;
#pragma unroll
    for (int nj = 0; nj < 4; nj++) {
      float bv = bias[ccol + nj * 16];
#pragma unroll
      for (int mi = 0; mi < 4; mi++)
#pragma unroll
        for (int r = 0; r < 4; r++)
          C[(size_t)(crow + mi * 16 + r) * N + ccol + nj * 16] =
              f2bf((acc[mi][nj][r] + bv) * scl);
    }
  } else {
    // ---- vhT epilogue: LDS transpose, then 128B-contiguous stores ----
    const int rl = wr * 64 + lg * 4;     // local f row base
    const int cl = wc * 64 + l15;        // local d col
#pragma unroll
    for (int nj = 0; nj < 4; nj++) {
      float bv = bias[ccol + nj * 16];
#pragma unroll
      for (int mi = 0; mi < 4; mi++)
#pragma unroll
        for (int r = 0; r < 4; r++)
          sbuf[(rl + mi * 16 + r) * 136 + cl + nj * 16] =
              f2bf(acc[mi][nj][r] + bv);
    }
    __syncthreads();
    const int drow = tid >> 1, seg = tid & 1;
    const int b = m0 >> 11;              // 128-row tile lies in one batch
    const int f0 = (m0 & 2047) + seg * 64;
    u16* dst = ovT + (size_t)(b * 1024 + n0 + drow) * 2048 + f0;
#pragma unroll
    for (int c = 0; c < 8; c++) {
      u16 tmp[8];
#pragma unroll
      for (int j = 0; j < 8; j++)
        tmp[j] = sbuf[(seg * 64 + c * 8 + j) * 136 + drow];
      ((uint4*)dst)[c] = pack8(tmp);
    }
  }
}

// ---------- out-projection GEMM: bf16 A * bf16 W^T -> fp32 ----------
__global__ __launch_bounds__(256) void gemm_out(
    const u16* __restrict__ A, const u16* __restrict__ Bt,
    float* __restrict__ C) {
  constexpr int K = 1024, N = 1024;
  __shared__ u16 lsA[128 * 32];
  __shared__ u16 lsB[128 * 32];
  const int tid = threadIdx.x;
  const int w = tid >> 6, lane = tid & 63;
  const int l15 = lane & 15, lg = lane >> 4;
  const int m0 = blockIdx.y << 7, n0 = blockIdx.x << 7;
  const int wr = w >> 1, wc = w & 1;

  f32x4 acc[4][4];
#pragma unroll
  for (int i = 0; i < 4; i++)
#pragma unroll
    for (int j = 0; j < 4; j++) acc[i][j] = f32x4{0.f, 0.f, 0.f, 0.f};

  const u16* As = A + (size_t)(m0 + w * 32 + (lane >> 2)) * K + (lane & 3) * 8;
  const u16* Bs = Bt + (size_t)(n0 + w * 32 + (lane >> 2)) * K + (lane & 3) * 8;
  u16* lA = &lsA[(w * 32) * 32];
  u16* lB = &lsB[(w * 32) * 32];

  for (int k0 = 0; k0 < K; k0 += 32) {
    gload16(As + k0, lA);
    gload16(As + 16 * K + k0, lA + 16 * 32);
    gload16(Bs + k0, lB);
    gload16(Bs + 16 * K + k0, lB + 16 * 32);
    __syncthreads();
    short8 af[4], bfv[4];
#pragma unroll
    for (int mi = 0; mi < 4; mi++)
      af[mi] = *(const short8*)&lsA[(wr * 64 + mi * 16 + l15) * 32 + lg * 8];
#pragma unroll
    for (int nj = 0; nj < 4; nj++)
      bfv[nj] = *(const short8*)&lsB[(wc * 64 + nj * 16 + l15) * 32 + lg * 8];
#pragma unroll
    for (int mi = 0; mi < 4; mi++)
#pragma unroll
      for (int nj = 0; nj < 4; nj++)
        acc[mi][nj] = __builtin_amdgcn_mfma_f32_16x16x32_bf16(af[mi], bfv[nj],
                                                              acc[mi][nj], 0, 0, 0);
    __syncthreads();
  }

  const int crow = m0 + wr * 64 + lg * 4;
  const int ccol = n0 + wc * 64 + l15;
#pragma unroll
  for (int nj = 0; nj < 4; nj++)
#pragma unroll
    for (int mi = 0; mi < 4; mi++)
#pragma unroll
      for (int r = 0; r < 4; r++)
        C[(size_t)(crow + mi * 16 + r) * N + ccol + nj * 16] = acc[mi][nj][r];
}

// ---------- flash attention v9 (byte-identical to r14, proven 112.7us) ----------
// grid 512 (XCD-swizzled): virt blk = ((b*16+h)*8 + qtile).
// 8 waves; wave owns 32 q-rows (q = lane&31); KTILE=64, dbuf, 1 barrier/tile.
__global__ __launch_bounds__(512, 4) void attn_fwd(
    const u16* __restrict__ qh, const u16* __restrict__ kh,
    const u16* __restrict__ vhT, const float* __restrict__ mask,
    const unsigned char* __restrict__ msum, u16* __restrict__ aout) {
  __shared__ u16 Kls[2][64][72];   // [buf][krow][d]
  __shared__ u16 Vls[2][64][72];   // [buf][d][kcol] (V^T)

  const int tid = threadIdx.x;
  const int w = tid >> 6, lane = tid & 63;
  const int l31 = lane & 31, hi = lane >> 5;
  const int blk = ((blockIdx.x & 7) << 6) | (blockIdx.x >> 3);
  const int qt = blk & 7, bh = blk >> 3, h = bh & 15, b = bh >> 4;
  const int frow = qt * 256 + w * 32;            // q row within batch b
  const size_t qrow0 = (size_t)b * 2048 + frow;  // q row in [8192]

  // Q B-frag: lane holds q-row = l31, d = ds*16 + hi*8 + j  (qh pre-scaled SC2)
  short8 qf[4];
#pragma unroll
  for (int ds = 0; ds < 4; ds++)
    qf[ds] = *(const short8*)&qh[(qrow0 + l31) * 1024 + h * 64 + ds * 16 + hi * 8];

  // loop-invariant zero bank: C-operand of each chain's first MFMA
  f32x16 zf;
#pragma unroll
  for (int i = 0; i < 16; i++) zf[i] = 0.f;

  f32x16 oacc[2];
#pragma unroll
  for (int i = 0; i < 16; i++) { oacc[0][i] = 0.f; oacc[1][i] = 0.f; }
  float m_run = 0.f, l_run = 0.f;  // log2 space; m stays 0 on unmasked path

  const int sr = tid >> 3, seg = tid & 7;  // staging: row 0..63, 16B chunk 0..7
  const u16* Ksrc = kh + ((size_t)b * 2048 + sr) * 1024 + h * 64 + seg * 8;
  const u16* Vsrc = vhT + ((size_t)bh * 64 + sr) * 2048 + seg * 8;
  const unsigned char* msrow = msum + (size_t)b * 65536 + frow + l31;

  uint4 ka0, va0;
  unsigned char mb, mbn;
  {  // prologue: tile 0 -> LDS[0]; prefetch tile 1 into regs
    uint4 x0 = *(const uint4*)Ksrc;
    uint4 y0 = *(const uint4*)Vsrc;
    *(uint4*)&Kls[0][sr][seg * 8] = x0;
    *(uint4*)&Vls[0][sr][seg * 8] = y0;
    ka0 = *(const uint4*)(Ksrc + 64 * 1024);
    va0 = *(const uint4*)(Vsrc + 64);
    mb = msrow[0];
    mbn = msrow[2048];
  }
  __syncthreads();

  for (int kt = 0; kt < 32; kt++) {
    const int cur = kt & 1;
    const int k0 = kt * 64;
    const int mflag = __any((int)mb);
    mb = mbn;

    // write prefetched tile kt+1 -> LDS[cur^1]; issue loads for tile kt+2
    if (kt < 31) {
      *(uint4*)&Kls[cur ^ 1][sr][seg * 8] = ka0;
      *(uint4*)&Vls[cur ^ 1][sr][seg * 8] = va0;
    }
    if (kt < 30) {
      ka0 = *(const uint4*)(Ksrc + (size_t)(kt + 2) * 64 * 1024);
      va0 = *(const uint4*)(Vsrc + (kt + 2) * 64);
      mbn = msrow[(size_t)(kt + 2) * 2048];
    }

    // ---- S^T = K * Q^T (log2 units): k = kb*32 + (reg&3)+8(reg>>2)+4hi, q = l31 ----
    f32x16 sacc[2];
#pragma unroll
    for (int kb = 0; kb < 2; kb++) {
      short8 kf[4];
#pragma unroll
      for (int ds = 0; ds < 4; ds++)
        kf[ds] = *(const short8*)&Kls[cur][kb * 32 + l31][ds * 16 + hi * 8];
      __builtin_amdgcn_s_setprio(1);
      sacc[kb] = __builtin_amdgcn_mfma_f32_32x32x16_bf16(kf[0], qf[0], zf, 0, 0, 0);
#pragma unroll
      for (int ds = 1; ds < 4; ds++)
        sacc[kb] = __builtin_amdgcn_mfma_f32_32x32x16_bf16(kf[ds], qf[ds],
                                                           sacc[kb], 0, 0, 0);
      __builtin_amdgcn_s_setprio(0);
    }

    // ---- masked path only: apply mask, exact max + defer-rescale ----
    if (mflag) {
      const size_t mrow = ((size_t)b * 2048 + frow + l31) * 2048 + (size_t)k0;
#pragma unroll
      for (int kb = 0; kb < 2; kb++)
#pragma unroll
        for (int r = 0; r < 16; r++) {
          float mv = mask[mrow + kb * 32 + (r & 3) + 8 * (r >> 2) + 4 * hi];
          sacc[kb][r] = fmaf(mv, MSC, sacc[kb][r]);
        }
      float mx[16];
#pragma unroll
      for (int r = 0; r < 16; r++) mx[r] = fmaxf(sacc[0][r], sacc[1][r]);
#pragma unroll
      for (int s = 8; s >= 1; s >>= 1)
#pragma unroll
        for (int r = 0; r < s; r++) mx[r] = fmaxf(mx[r], mx[r + s]);
      float tm = mx[0];
      tm = fmaxf(tm, __shfl_xor(tm, 32, 64));
      if (!__all(tm <= m_run + THR)) {
        float mnew = fmaxf(m_run, tm);
        float al = exp2f(m_run - mnew);
        m_run = mnew;
        l_run *= al;
#pragma unroll
        for (int r = 0; r < 16; r++) {
          float alr = __shfl(al, (r & 3) + 8 * (r >> 2) + 4 * hi, 64);
          oacc[0][r] *= alr;
          oacc[1][r] *= alr;
        }
      }
    }

    // ---- exp + sum + pack + permlane32_swap (wave-uniform offset branch) ----
    float rsp = 0.f, rsq = 0.f;
    unsigned pw[16];
    if (m_run == 0.f) {  // fast path: bare exp2, no offset
#pragma unroll
      for (int kb = 0; kb < 2; kb++)
#pragma unroll
        for (int jp = 0; jp < 2; jp++) {
          float e[8];
#pragma unroll
          for (int t = 0; t < 8; t++)
            e[t] = exp2f(sacc[kb][8 * jp + t]);
          rsp += (e[0] + e[1]) + (e[2] + e[3]);
          rsq += (e[4] + e[5]) + (e[6] + e[7]);
          unsigned ye0 = cvtpk(e[0], e[1]);
          unsigned ye1 = cvtpk(e[2], e[3]);
          unsigned xo0 = cvtpk(e[4], e[5]);
          unsigned xo1 = cvtpk(e[6], e[7]);
          asm volatile("v_permlane32_swap_b32 %0, %1" : "+v"(ye0), "+v"(xo0));
          asm volatile("v_permlane32_swap_b32 %0, %1" : "+v"(ye1), "+v"(xo1));
          const int kk = kb * 2 + jp;
          pw[kk * 4 + 0] = ye0;
          pw[kk * 4 + 1] = ye1;
          pw[kk * 4 + 2] = xo0;
          pw[kk * 4 + 3] = xo1;
        }
    } else {  // masked-history path: offset by m_run
      const float mm = m_run;
#pragma unroll
      for (int kb = 0; kb < 2; kb++)
#pragma unroll
        for (int jp = 0; jp < 2; jp++) {
          float e[8];
#pragma unroll
          for (int t = 0; t < 8; t++)
            e[t] = exp2f(sacc[kb][8 * jp + t] - mm);
          rsp += (e[0] + e[1]) + (e[2] + e[3]);
          rsq += (e[4] + e[5]) + (e[6] + e[7]);
          unsigned ye0 = cvtpk(e[0], e[1]);
          unsigned ye1 = cvtpk(e[2], e[3]);
          unsigned xo0 = cvtpk(e[4], e[5]);
          unsigned xo1 = cvtpk(e[6], e[7]);
          asm volatile("v_permlane32_swap_b32 %0, %1" : "+v"(ye0), "+v"(xo0));
          asm volatile("v_permlane32_swap_b32 %0, %1" : "+v"(ye1), "+v"(xo1));
          const int kk = kb * 2 + jp;
          pw[kk * 4 + 0] = ye0;
          pw[kk * 4 + 1] = ye1;
          pw[kk * 4 + 2] = xo0;
          pw[kk * 4 + 3] = xo1;
        }
    }
    float rs = rsp + rsq;
    rs += __shfl_xor(rs, 32, 64);
    l_run += rs;

    // ---- O += P * V ----
#pragma unroll
    for (int dn = 0; dn < 2; dn++) {
      short8 vf[4];
#pragma unroll
      for (int kk = 0; kk < 4; kk++)
        vf[kk] = *(const short8*)&Vls[cur][dn * 32 + l31][kk * 16 + hi * 8];
      __builtin_amdgcn_s_setprio(1);
#pragma unroll
      for (int kk = 0; kk < 4; kk++) {
        uint4 t4 = {pw[kk * 4 + 0], pw[kk * 4 + 1], pw[kk * 4 + 2], pw[kk * 4 + 3]};
        oacc[dn] = __builtin_amdgcn_mfma_f32_32x32x16_bf16(
            *(short8*)&t4, vf[kk], oacc[dn], 0, 0, 0);
      }
      __builtin_amdgcn_s_setprio(0);
    }

    __syncthreads();
  }

  // ---- epilogue: O / l ----
  float inv = 1.0f / l_run;
#pragma unroll
  for (int r = 0; r < 16; r++) {
    const int qr = (r & 3) + 8 * (r >> 2) + 4 * hi;
    float invr = __shfl(inv, qr, 64);
    aout[(qrow0 + qr) * 1024 + h * 64 + l31] = f2bf(oacc[0][r] * invr);
    aout[(qrow0 + qr) * 1024 + h * 64 + 32 + l31] = f2bf(oacc[1][r] * invr);
  }
}

extern "C" void kernel_launch(void* const* d_in, const int* in_sizes, int n_in,
                              void* d_out, int out_size, void* d_ws, size_t ws_size,
                              hipStream_t stream) {
  (void)in_sizes; (void)n_in; (void)out_size; (void)ws_size;
  const float* q    = (const float*)d_in[0];
  const float* k    = (const float*)d_in[1];
  const float* v    = (const float*)d_in[2];
  const float* mask = (const float*)d_in[3];
  const float* qw_w = (const float*)d_in[4];
  const float* qw_b = (const float*)d_in[5];
  const float* kw_w = (const float*)d_in[6];
  const float* kw_b = (const float*)d_in[7];
  const float* vw_w = (const float*)d_in[8];
  const float* vw_b = (const float*)d_in[9];
  const float* wo   = (const float*)d_in[10];

  // workspace layout (u16 elems); total ~40.3 MB
  u16* vhT = (u16*)d_ws;               // 4096*2048 = 16 MB
  u16* qwT = vhT + 4096 * 2048;        // 4x 1024*1024 = 8 MB
  u16* kwT = qwT + 1024 * 1024;
  u16* vwT = kwT + 1024 * 1024;
  u16* woT = vwT + 1024 * 1024;
  u16* attn_o = woT + 1024 * 1024;     // 8192*1024 = 16 MB
  unsigned char* msumb = (unsigned char*)(attn_o + 8192 * 1024);  // 256 KB
  u16* qh = (u16*)d_out;               // park bf16 qh/kh in d_out (exact fit)
  u16* kh = qh + 8192 * 1024;

  wtrans<<<dim3(16, 16, 4), 256, 0, stream>>>(qw_w, kw_w, vw_w, wo,
                                              qwT, kwT, vwT, woT);
  gemm_proj3<<<dim3(8, 64, 3), 256, 0, stream>>>(q, k, v, qwT, kwT, vwT,
                                                 qw_b, kw_b, vw_b, qh, kh, vhT);
  masksum<<<1024, 256, 0, stream>>>(mask, msumb);  // right before attn: L2 flush
  attn_fwd<<<512, 512, 0, stream>>>(qh, kh, vhT, mask, msumb, attn_o);
  gemm_out<<<dim3(8, 64), 256, 0, stream>>>(attn_o, woT, (float*)d_out);
}